// Round 10
// baseline (174.603 us; speedup 1.0000x reference)
//
#include <hip/hip_runtime.h>
#include <hip/hip_bf16.h>
#include <stdint.h>

// MoE experts: E=8, T=2048, H=1024, I=2048, contiguous token groups.
// up = h@w1_e ; up_r = h@w3_e ; gated = silu(up)*up_r ; out = gated@w2_e
// bf16 MFMA compute, fp32 accumulate, weights cvt'd fp32->bf16 on the fly.
//
// Round-10: gate fused into the w3-pass EPILOGUE (not the per-phase path --
// r6 lesson). moe_upg<0>: up = hb@w1. moe_upg<1>: reads up tile (cache-hot),
// writes gated = silu(up)*(hb@w3) directly. Gate kernel eliminated (-7us,
// -24MB churn in the window between weight streams and moe_down). down
// unchanged to test whether its fast mode (0.4us/phase, w2 L3-resident)
// returns when the inter-replay traffic window shrinks.

#define NE 8
#define NT 2048
#define NH 1024
#define NI 2048

typedef __attribute__((ext_vector_type(8))) short bh8;      // 8 bf16
typedef __attribute__((ext_vector_type(4))) short bh4;      // 4 bf16
typedef __attribute__((ext_vector_type(4))) float f32x4;
typedef __attribute__((ext_vector_type(2))) float f32x2;
typedef __attribute__((ext_vector_type(4))) float float4v;

#define BARRIER() asm volatile("s_waitcnt lgkmcnt(0)\n\ts_barrier" ::: "memory")

static __device__ __forceinline__ unsigned short f2bf(float f) {
  __hip_bfloat16 h = __float2bfloat16(f);   // RNE
  return *reinterpret_cast<unsigned short*>(&h);
}
static __device__ __forceinline__ float bf2f(unsigned short s) {
  return __uint_as_float(((unsigned int)s) << 16);
}

// ---- hiddens fp32 -> bf16 (ws) ----
__global__ __launch_bounds__(256)
void cvt_h_kernel(const float* __restrict__ x, unsigned short* __restrict__ y) {
  int i = blockIdx.x * 256 + threadIdx.x;           // one bh8 per thread
  const float4v* xv = reinterpret_cast<const float4v*>(x);
  float4v a = xv[2 * i], b = xv[2 * i + 1];
  union { bh8 v; unsigned short u[8]; } o;
  o.u[0] = f2bf(a[0]); o.u[1] = f2bf(a[1]); o.u[2] = f2bf(a[2]); o.u[3] = f2bf(a[3]);
  o.u[4] = f2bf(b[0]); o.u[5] = f2bf(b[1]); o.u[6] = f2bf(b[2]); o.u[7] = f2bf(b[3]);
  reinterpret_cast<bh8*>(y)[i] = o.v;
}

// LDS layouts: [row][k 32] bf16, 4 x 16B slots per row,
// slot' = slot ^ ((row>>1)&3). Fragment read = single ds_read_b128.

// ============ UPG-GEMM: O = hb @ W (GATE=0) or gated = silu(up)*(hb@W) (GATE=1) ============
// BM=128 BN=128 BK=32, 8 waves, dist-2 pipeline, 32 phases (K=NH).
template <int GATE>
__global__ __launch_bounds__(512, 2)
void moe_upg(const unsigned short* __restrict__ hb,   // [T][H] bf16
             const float* __restrict__ W,             // [E][H][I]
             const int* __restrict__ bsz,
             const unsigned short* __restrict__ upin, // [T][I] bf16 (GATE=1)
             unsigned short* __restrict__ O) {        // [T][I] bf16
  const int NWG = 2048;                        // nt(16) x e(8) x mt(16)
  const int wg = (blockIdx.x & 7) * (NWG >> 3) + (blockIdx.x >> 3);
  const int mt = wg & 15;
  const int e = (wg >> 4) & 7;
  const int nt = wg >> 7;                      // 0..15

  int off = 0;
#pragma unroll
  for (int j = 0; j < NE; ++j) { int v = bsz[j]; off += (j < e) ? v : 0; }
  const int te = bsz[e];
  if (mt * 128 >= te) return;

  const int tid = threadIdx.x;
  const int l = tid & 63, w = tid >> 6;
  const int wr = w >> 2, wc = w & 3;

  __shared__ __align__(16) unsigned short As[2][128 * 32];
  __shared__ __align__(16) unsigned short Bs[2][128 * 32];

  const int row0 = off + mt * 128;
  const int col0 = nt * 128;

  int gr = row0 + (tid >> 2); if (gr > NT - 1) gr = NT - 1;
  const unsigned short* agA = hb + (size_t)gr * NH + (tid & 3) * 8;
  const int awo = (tid >> 2) * 32 + (((tid & 3) ^ ((tid >> 3) & 3)) * 8);

  const int n0 = 2 * l;
  const float* wp = W + (size_t)e * NH * NI + (size_t)(4 * w) * NI + (col0 + n0);
  const int bwo = n0 * 32 + (((w >> 1) ^ (l & 3)) * 8) + (w & 1) * 4;

  const int arow = wr * 64 + (l & 15);
  const int fslA = ((l >> 4) ^ ((l >> 1) & 3)) * 8;
  const int nbase = wc * 32 + (l & 15);
  const int bsl = ((l >> 4) ^ ((nbase >> 1) & 3)) * 8;

  f32x4 acc[4][2] = {};
  bh8 rA0, rA1;
  f32x2 rb0[4], rb1[4];

  auto issue = [&](int t, bh8& rA_, f32x2 (&rb_)[4]) {
    const int k0 = t * 32;
    rA_ = *(const bh8*)(agA + k0);
#pragma unroll
    for (int j = 0; j < 4; ++j) rb_[j] = *(const f32x2*)(wp + (size_t)(k0 + j) * NI);
  };
  auto stage = [&](int b, bh8& rA_, f32x2 (&rb_)[4]) {
    *(bh8*)(&As[b][awo]) = rA_;
    bh4 q0, q1;
#pragma unroll
    for (int j = 0; j < 4; ++j) {
      q0[j] = (short)f2bf(rb_[j][0]); q1[j] = (short)f2bf(rb_[j][1]);
    }
    *(bh4*)(&Bs[b][bwo]) = q0;
    *(bh4*)(&Bs[b][bwo + 32]) = q1;
  };
  auto mfma_step = [&](int b) {
    bh8 af[4];
#pragma unroll
    for (int m = 0; m < 4; ++m)
      af[m] = *(const bh8*)(&As[b][(arow + m * 16) * 32 + fslA]);
    __builtin_amdgcn_s_setprio(1);
#pragma unroll
    for (int nf = 0; nf < 2; ++nf) {
      bh8 bf = *(const bh8*)(&Bs[b][(nbase + nf * 16) * 32 + bsl]);
#pragma unroll
      for (int m = 0; m < 4; ++m)
        acc[m][nf] = __builtin_amdgcn_mfma_f32_16x16x32_bf16(af[m], bf, acc[m][nf], 0, 0, 0);
    }
    __builtin_amdgcn_s_setprio(0);
  };

  issue(0, rA0, rb0);
  issue(1, rA1, rb1);
  stage(0, rA0, rb0);
  BARRIER();

#pragma unroll 1
  for (int u = 0; u < 16; ++u) {
    const int t0 = 2 * u;
    if (t0 + 2 < 32) issue(t0 + 2, rA0, rb0);
    mfma_step(0);
    stage(1, rA1, rb1);
    BARRIER();
    if (t0 + 3 < 32) issue(t0 + 3, rA1, rb1);
    mfma_step(1);
    if (t0 + 2 < 32) stage(0, rA0, rb0);
    BARRIER();
  }

  // epilogue: GATE=0 -> O = acc ; GATE=1 -> O = silu(up)*acc  (once/element,
  // off the per-phase path; up tile is L2/L3-hot from the previous dispatch)
#pragma unroll
  for (int m = 0; m < 4; ++m) {
#pragma unroll
    for (int r = 0; r < 4; ++r) {
      int trow = mt * 128 + wr * 64 + m * 16 + (l >> 4) * 4 + r;
      if (trow < te) {
        size_t base = (size_t)(off + trow) * NI + col0 + wc * 32 + (l & 15);
#pragma unroll
        for (int nf = 0; nf < 2; ++nf) {
          float g = acc[m][nf][r];
          if (GATE) {
            float uu = bf2f(upin[base + nf * 16]);
            g = (uu / (1.f + __expf(-uu))) * g;
          }
          O[base + nf * 16] = f2bf(g);
        }
      }
    }
  }
}

// ============ DOWN-GEMM: out = gated @ w2 -> fp32 (unchanged r8/r9) ============
// BM=128 BN=128 BK=32, 8 waves, dist-2 pipeline, 64 phases.
__global__ __launch_bounds__(512, 2)
void moe_down(const unsigned short* __restrict__ gated,  // [T][I] bf16
              const float* __restrict__ w2,              // [E][I][H]
              const int* __restrict__ bsz,
              float* __restrict__ out) {                 // [T][H] fp32
  const int NWG = 1024;                        // nt(8) x e(8) x mt(16)
  const int wg = (blockIdx.x & 7) * (NWG >> 3) + (blockIdx.x >> 3);
  const int mt = wg & 15;
  const int e = (wg >> 4) & 7;
  const int nt = wg >> 7;

  int off = 0;
#pragma unroll
  for (int j = 0; j < NE; ++j) { int v = bsz[j]; off += (j < e) ? v : 0; }
  const int te = bsz[e];
  if (mt * 128 >= te) return;

  const int tid = threadIdx.x;
  const int l = tid & 63, w = tid >> 6;
  const int wr = w >> 2, wc = w & 3;

  __shared__ __align__(16) unsigned short As[2][128 * 32];
  __shared__ __align__(16) unsigned short Bs[2][128 * 32];

  const int row0 = off + mt * 128;
  const int col0 = nt * 128;

  int gr = row0 + (tid >> 2); if (gr > NT - 1) gr = NT - 1;
  const unsigned short* agA = gated + (size_t)gr * NI + (tid & 3) * 8;
  const int awo = (tid >> 2) * 32 + (((tid & 3) ^ ((tid >> 3) & 3)) * 8);

  const int n0 = 2 * l;
  const float* w2p = w2 + (size_t)e * NI * NH + (size_t)(4 * w) * NH + (col0 + n0);
  const int bwo = n0 * 32 + (((w >> 1) ^ (l & 3)) * 8) + (w & 1) * 4;

  const int arow = wr * 64 + (l & 15);
  const int fslA = ((l >> 4) ^ ((l >> 1) & 3)) * 8;
  const int nbase = wc * 32 + (l & 15);
  const int bsl = ((l >> 4) ^ ((nbase >> 1) & 3)) * 8;

  f32x4 acc[4][2] = {};
  bh8 rA0, rA1;
  f32x2 rb0[4], rb1[4];

  auto issue = [&](int t, bh8& rA_, f32x2 (&rb_)[4]) {
    const int k0 = t * 32;
    rA_ = *(const bh8*)(agA + k0);
#pragma unroll
    for (int j = 0; j < 4; ++j) rb_[j] = *(const f32x2*)(w2p + (size_t)(k0 + j) * NH);
  };
  auto stage = [&](int b, bh8& rA_, f32x2 (&rb_)[4]) {
    *(bh8*)(&As[b][awo]) = rA_;
    bh4 q0, q1;
#pragma unroll
    for (int j = 0; j < 4; ++j) {
      q0[j] = (short)f2bf(rb_[j][0]); q1[j] = (short)f2bf(rb_[j][1]);
    }
    *(bh4*)(&Bs[b][bwo]) = q0;
    *(bh4*)(&Bs[b][bwo + 32]) = q1;
  };
  auto mfma_step = [&](int b) {
    bh8 af[4];
#pragma unroll
    for (int m = 0; m < 4; ++m)
      af[m] = *(const bh8*)(&As[b][(arow + m * 16) * 32 + fslA]);
    __builtin_amdgcn_s_setprio(1);
#pragma unroll
    for (int nf = 0; nf < 2; ++nf) {
      bh8 bf = *(const bh8*)(&Bs[b][(nbase + nf * 16) * 32 + bsl]);
#pragma unroll
      for (int m = 0; m < 4; ++m)
        acc[m][nf] = __builtin_amdgcn_mfma_f32_16x16x32_bf16(af[m], bf, acc[m][nf], 0, 0, 0);
    }
    __builtin_amdgcn_s_setprio(0);
  };

  issue(0, rA0, rb0);
  issue(1, rA1, rb1);
  stage(0, rA0, rb0);
  BARRIER();

#pragma unroll 1
  for (int u = 0; u < 32; ++u) {
    const int t0 = 2 * u;
    if (t0 + 2 < 64) issue(t0 + 2, rA0, rb0);
    mfma_step(0);
    stage(1, rA1, rb1);
    BARRIER();
    if (t0 + 3 < 64) issue(t0 + 3, rA1, rb1);
    mfma_step(1);
    if (t0 + 2 < 64) stage(0, rA0, rb0);
    BARRIER();
  }

#pragma unroll
  for (int m = 0; m < 4; ++m) {
#pragma unroll
    for (int r = 0; r < 4; ++r) {
      int trow = mt * 128 + wr * 64 + m * 16 + (l >> 4) * 4 + r;
      if (trow < te) {
        size_t base = (size_t)(off + trow) * NH + col0 + wc * 32 + (l & 15);
#pragma unroll
        for (int nf = 0; nf < 2; ++nf)
          out[base + nf * 16] = acc[m][nf][r];
      }
    }
  }
}

extern "C" void kernel_launch(void* const* d_in, const int* in_sizes, int n_in,
                              void* d_out, int out_size, void* d_ws, size_t ws_size,
                              hipStream_t stream) {
  const float* hiddens = (const float*)d_in[0];
  const float* w1 = (const float*)d_in[1];
  const float* w2 = (const float*)d_in[2];
  const float* w3 = (const float*)d_in[3];
  const int* bsz = (const int*)d_in[4];
  float* out = (float*)d_out;

  // ws: [0,4MB) hiddens bf16 ; [4,12MB) up ; [12,20MB) gated
  unsigned short* hb = (unsigned short*)d_ws;
  unsigned short* up = hb + (size_t)NT * NH;
  unsigned short* gated = up + (size_t)NT * NI;

  cvt_h_kernel<<<dim3(NT * NH / 8 / 256), dim3(256), 0, stream>>>(hiddens, hb);
  moe_upg<0><<<dim3(2048), dim3(512), 0, stream>>>(hb, w1, bsz, up, up);
  moe_upg<1><<<dim3(2048), dim3(512), 0, stream>>>(hb, w3, bsz, up, gated);
  moe_down<<<dim3(1024), dim3(512), 0, stream>>>(gated, w2, bsz, out);
}

// Round 11
// 161.355 us; speedup vs baseline: 1.0821x; 1.0821x over previous
//
#include <hip/hip_runtime.h>
#include <hip/hip_bf16.h>
#include <stdint.h>

// MoE experts: E=8, T=2048, H=1024, I=2048, contiguous token groups.
// up = h@w1_e ; up_r = h@w3_e ; gated = silu(up)*up_r ; out = gated@w2_e
// bf16 MFMA compute, fp32 accumulate, weights cvt'd fp32->bf16 on the fly.
//
// Round-11: BN 128->64 to multiply working blocks (the measured binding
// resource: every block stages ~19-25 GB/s HBM-cold; time = staged_bytes /
// (working_blocks x rate); ragged mt keeps grids at 144-288 working blocks
// with half the chip idle). Now: up 576 working blocks/matrix (2.25/CU),
// down 288. Per-phase staged 16KB, LDS 24KB (4 blocks/CU co-residable).
// Pipeline (dist-2, lgkm-only barriers, setprio) and swizzles unchanged.

#define NE 8
#define NT 2048
#define NH 1024
#define NI 2048

typedef __attribute__((ext_vector_type(8))) short bh8;      // 8 bf16
typedef __attribute__((ext_vector_type(4))) short bh4;      // 4 bf16
typedef __attribute__((ext_vector_type(4))) float f32x4;
typedef __attribute__((ext_vector_type(4))) float float4v;

#define BARRIER() asm volatile("s_waitcnt lgkmcnt(0)\n\ts_barrier" ::: "memory")

static __device__ __forceinline__ unsigned short f2bf(float f) {
  __hip_bfloat16 h = __float2bfloat16(f);   // RNE
  return *reinterpret_cast<unsigned short*>(&h);
}
static __device__ __forceinline__ float bf2f(unsigned short s) {
  return __uint_as_float(((unsigned int)s) << 16);
}

// ---- hiddens fp32 -> bf16 (ws) ----
__global__ __launch_bounds__(256)
void cvt_h_kernel(const float* __restrict__ x, unsigned short* __restrict__ y) {
  int i = blockIdx.x * 256 + threadIdx.x;           // one bh8 per thread
  const float4v* xv = reinterpret_cast<const float4v*>(x);
  float4v a = xv[2 * i], b = xv[2 * i + 1];
  union { bh8 v; unsigned short u[8]; } o;
  o.u[0] = f2bf(a[0]); o.u[1] = f2bf(a[1]); o.u[2] = f2bf(a[2]); o.u[3] = f2bf(a[3]);
  o.u[4] = f2bf(b[0]); o.u[5] = f2bf(b[1]); o.u[6] = f2bf(b[2]); o.u[7] = f2bf(b[3]);
  reinterpret_cast<bh8*>(y)[i] = o.v;
}

// LDS layouts: [row][k 32] bf16, 4 x 16B slots per row,
// physical slot = kslot ^ ((row>>1)&3). Fragment read = single ds_read_b128.

// ============ UPG-GEMM: O = hb @ W (GATE=0) or gated = silu(up)*(hb@W) (GATE=1) ============
// BM=128 BN=64 BK=32, 8 waves (2x4 -> 64x16/wave), dist-2, 32 phases.
template <int GATE>
__global__ __launch_bounds__(512, 2)
void moe_upg(const unsigned short* __restrict__ hb,   // [T][H] bf16
             const float* __restrict__ W,             // [E][H][I]
             const int* __restrict__ bsz,
             const unsigned short* __restrict__ upin, // [T][I] bf16 (GATE=1)
             unsigned short* __restrict__ O) {        // [T][I] bf16
  const int NWG = 4096;                        // nt(32) x e(8) x mt(16)
  const int wg = (blockIdx.x & 7) * (NWG >> 3) + (blockIdx.x >> 3);
  const int mt = wg & 15;
  const int e = (wg >> 4) & 7;
  const int nt = wg >> 7;                      // 0..31

  int off = 0;
#pragma unroll
  for (int j = 0; j < NE; ++j) { int v = bsz[j]; off += (j < e) ? v : 0; }
  const int te = bsz[e];
  if (mt * 128 >= te) return;

  const int tid = threadIdx.x;
  const int l = tid & 63, w = tid >> 6;
  const int wr = w >> 2, wc = w & 3;           // wave tile 64m x 16n

  __shared__ __align__(16) unsigned short As[2][128 * 32];  // 2 x 8KB
  __shared__ __align__(16) unsigned short Bs[2][64 * 32];   // 2 x 4KB

  const int row0 = off + mt * 128;
  const int col0 = nt * 64;

  // A: thread owns row tid>>2, slot tid&3 (bh8 load, swizzled ds_write)
  int gr = row0 + (tid >> 2); if (gr > NT - 1) gr = NT - 1;
  const unsigned short* agA = hb + (size_t)gr * NH + (tid & 3) * 8;
  const int awo = (tid >> 2) * 32 + (((tid & 3) ^ ((tid >> 3) & 3)) * 8);

  // B: lane owns col l; wave w owns k-quad 4w..4w+3 (4 x 4B loads, 256B/row
  // coalesced across lanes). One ds_write_b64 per thread.
  const float* wp = W + (size_t)e * NH * NI + (size_t)(4 * w) * NI + (col0 + l);
  const int bwo = l * 32 + (((w >> 1) ^ ((l >> 1) & 3)) * 8) + (w & 1) * 4;

  const int arow = wr * 64 + (l & 15);
  const int fslA = ((l >> 4) ^ ((l >> 1) & 3)) * 8;
  const int nbase = wc * 16 + (l & 15);
  const int bsl = ((l >> 4) ^ ((nbase >> 1) & 3)) * 8;

  f32x4 acc[4] = {};
  bh8 rA0, rA1;
  float rb0[4], rb1[4];

  auto issue = [&](int t, bh8& rA_, float (&rb_)[4]) {
    const int k0 = t * 32;
    rA_ = *(const bh8*)(agA + k0);
#pragma unroll
    for (int j = 0; j < 4; ++j) rb_[j] = *(wp + (size_t)(k0 + j) * NI);
  };
  auto stage = [&](int b, bh8& rA_, float (&rb_)[4]) {
    *(bh8*)(&As[b][awo]) = rA_;
    bh4 q;
#pragma unroll
    for (int j = 0; j < 4; ++j) q[j] = (short)f2bf(rb_[j]);
    *(bh4*)(&Bs[b][bwo]) = q;
  };
  auto mfma_step = [&](int b) {
    bh8 af[4];
#pragma unroll
    for (int m = 0; m < 4; ++m)
      af[m] = *(const bh8*)(&As[b][(arow + m * 16) * 32 + fslA]);
    bh8 bf = *(const bh8*)(&Bs[b][nbase * 32 + bsl]);
    __builtin_amdgcn_s_setprio(1);
#pragma unroll
    for (int m = 0; m < 4; ++m)
      acc[m] = __builtin_amdgcn_mfma_f32_16x16x32_bf16(af[m], bf, acc[m], 0, 0, 0);
    __builtin_amdgcn_s_setprio(0);
  };

  issue(0, rA0, rb0);
  issue(1, rA1, rb1);
  stage(0, rA0, rb0);
  BARRIER();

#pragma unroll 1
  for (int u = 0; u < 16; ++u) {
    const int t0 = 2 * u;
    if (t0 + 2 < 32) issue(t0 + 2, rA0, rb0);
    mfma_step(0);
    stage(1, rA1, rb1);
    BARRIER();
    if (t0 + 3 < 32) issue(t0 + 3, rA1, rb1);
    mfma_step(1);
    if (t0 + 2 < 32) stage(0, rA0, rb0);
    BARRIER();
  }

  // epilogue: GATE=0 -> O = acc ; GATE=1 -> O = silu(up)*acc (off-phase path)
#pragma unroll
  for (int m = 0; m < 4; ++m) {
#pragma unroll
    for (int r = 0; r < 4; ++r) {
      int trow = mt * 128 + wr * 64 + m * 16 + (l >> 4) * 4 + r;
      if (trow < te) {
        size_t base = (size_t)(off + trow) * NI + col0 + wc * 16 + (l & 15);
        float g = acc[m][r];
        if (GATE) {
          float uu = bf2f(upin[base]);
          g = (uu / (1.f + __expf(-uu))) * g;
        }
        O[base] = f2bf(g);
      }
    }
  }
}

// ============ DOWN-GEMM: out = gated @ w2 -> fp32 ============
// BM=128 BN=64 BK=32, 8 waves, dist-2, 64 phases.
__global__ __launch_bounds__(512, 2)
void moe_down(const unsigned short* __restrict__ gated,  // [T][I] bf16
              const float* __restrict__ w2,              // [E][I][H]
              const int* __restrict__ bsz,
              float* __restrict__ out) {                 // [T][H] fp32
  const int NWG = 2048;                        // nt(16) x e(8) x mt(16)
  const int wg = (blockIdx.x & 7) * (NWG >> 3) + (blockIdx.x >> 3);
  const int mt = wg & 15;
  const int e = (wg >> 4) & 7;
  const int nt = wg >> 7;                      // 0..15

  int off = 0;
#pragma unroll
  for (int j = 0; j < NE; ++j) { int v = bsz[j]; off += (j < e) ? v : 0; }
  const int te = bsz[e];
  if (mt * 128 >= te) return;

  const int tid = threadIdx.x;
  const int l = tid & 63, w = tid >> 6;
  const int wr = w >> 2, wc = w & 3;

  __shared__ __align__(16) unsigned short As[2][128 * 32];
  __shared__ __align__(16) unsigned short Bs[2][64 * 32];

  const int row0 = off + mt * 128;
  const int col0 = nt * 64;

  int gr = row0 + (tid >> 2); if (gr > NT - 1) gr = NT - 1;
  const unsigned short* agA = gated + (size_t)gr * NI + (tid & 3) * 8;
  const int awo = (tid >> 2) * 32 + (((tid & 3) ^ ((tid >> 3) & 3)) * 8);

  const float* wp = w2 + (size_t)e * NI * NH + (size_t)(4 * w) * NH + (col0 + l);
  const int bwo = l * 32 + (((w >> 1) ^ ((l >> 1) & 3)) * 8) + (w & 1) * 4;

  const int arow = wr * 64 + (l & 15);
  const int fslA = ((l >> 4) ^ ((l >> 1) & 3)) * 8;
  const int nbase = wc * 16 + (l & 15);
  const int bsl = ((l >> 4) ^ ((nbase >> 1) & 3)) * 8;

  f32x4 acc[4] = {};
  bh8 rA0, rA1;
  float rb0[4], rb1[4];

  auto issue = [&](int t, bh8& rA_, float (&rb_)[4]) {
    const int k0 = t * 32;
    rA_ = *(const bh8*)(agA + k0);
#pragma unroll
    for (int j = 0; j < 4; ++j) rb_[j] = *(wp + (size_t)(k0 + j) * NH);
  };
  auto stage = [&](int b, bh8& rA_, float (&rb_)[4]) {
    *(bh8*)(&As[b][awo]) = rA_;
    bh4 q;
#pragma unroll
    for (int j = 0; j < 4; ++j) q[j] = (short)f2bf(rb_[j]);
    *(bh4*)(&Bs[b][bwo]) = q;
  };
  auto mfma_step = [&](int b) {
    bh8 af[4];
#pragma unroll
    for (int m = 0; m < 4; ++m)
      af[m] = *(const bh8*)(&As[b][(arow + m * 16) * 32 + fslA]);
    bh8 bf = *(const bh8*)(&Bs[b][nbase * 32 + bsl]);
    __builtin_amdgcn_s_setprio(1);
#pragma unroll
    for (int m = 0; m < 4; ++m)
      acc[m] = __builtin_amdgcn_mfma_f32_16x16x32_bf16(af[m], bf, acc[m], 0, 0, 0);
    __builtin_amdgcn_s_setprio(0);
  };

  issue(0, rA0, rb0);
  issue(1, rA1, rb1);
  stage(0, rA0, rb0);
  BARRIER();

#pragma unroll 1
  for (int u = 0; u < 32; ++u) {
    const int t0 = 2 * u;
    if (t0 + 2 < 64) issue(t0 + 2, rA0, rb0);
    mfma_step(0);
    stage(1, rA1, rb1);
    BARRIER();
    if (t0 + 3 < 64) issue(t0 + 3, rA1, rb1);
    mfma_step(1);
    if (t0 + 2 < 64) stage(0, rA0, rb0);
    BARRIER();
  }

#pragma unroll
  for (int m = 0; m < 4; ++m) {
#pragma unroll
    for (int r = 0; r < 4; ++r) {
      int trow = mt * 128 + wr * 64 + m * 16 + (l >> 4) * 4 + r;
      if (trow < te) {
        size_t base = (size_t)(off + trow) * NH + col0 + wc * 16 + (l & 15);
        out[base] = acc[m][r];
      }
    }
  }
}

extern "C" void kernel_launch(void* const* d_in, const int* in_sizes, int n_in,
                              void* d_out, int out_size, void* d_ws, size_t ws_size,
                              hipStream_t stream) {
  const float* hiddens = (const float*)d_in[0];
  const float* w1 = (const float*)d_in[1];
  const float* w2 = (const float*)d_in[2];
  const float* w3 = (const float*)d_in[3];
  const int* bsz = (const int*)d_in[4];
  float* out = (float*)d_out;

  // ws: [0,4MB) hiddens bf16 ; [4,12MB) up ; [12,20MB) gated
  unsigned short* hb = (unsigned short*)d_ws;
  unsigned short* up = hb + (size_t)NT * NH;
  unsigned short* gated = up + (size_t)NT * NI;

  cvt_h_kernel<<<dim3(NT * NH / 8 / 256), dim3(256), 0, stream>>>(hiddens, hb);
  moe_upg<0><<<dim3(4096), dim3(512), 0, stream>>>(hb, w1, bsz, up, up);
  moe_upg<1><<<dim3(4096), dim3(512), 0, stream>>>(hb, w3, bsz, up, gated);
  moe_down<<<dim3(2048), dim3(512), 0, stream>>>(gated, w2, bsz, out);
}